// Round 2
// baseline (158.743 us; speedup 1.0000x reference)
//
#include <hip/hip_runtime.h>
#include <stdint.h>

// GAT_88252987998923 — analytic collapse (all fp32, per reference dtypes):
// Output depends only on g = h_prime.mean(axis=0). Mean of a scatter-add is the
// sum of all edge contributions / N (scatter index irrelevant). Segment-softmax
// alphas sum to exactly 1 per dst segment, and each edge contributes
// alpha_e * (nodes[dst_e] @ W[s]) ⇒
//   g = (1/N) * Σ_s (Σ_{n: indeg_s(n)>0} nodes[n]) @ W[s]
// att_w/att_b/softmax/per-edge gathers cancel entirely.
// Pipeline: memset ws → flag dst nodes → masked column sums → matvec + MLP.

#define NN   100000
#define DD   128
#define EE   600000
#define SS   2
#define HIDN 80

__device__ __forceinline__ float leaky(float x) { return x > 0.f ? x : 0.01f * x; }

// Mark nodes that have >=1 incoming edge per edge-set s. Races benign (store 1).
__global__ __launch_bounds__(256) void k_flags(const int2* __restrict__ e2,
                                               uint8_t* __restrict__ flags) {
    int i = blockIdx.x * 256 + threadIdx.x;
    if (i < SS * EE) {
        int dst = e2[i].y;                 // edges[s][e][1]
        int s   = (i >= EE) ? 1 : 0;
        flags[s * NN + dst] = 1;
    }
}

// Masked column sums: sums[s*128 + d] = Σ_{n: flags[s][n]} nodes[n][d]
__global__ __launch_bounds__(256) void k_msum(const float4* __restrict__ nodes4,
                                              const uint8_t* __restrict__ flags,
                                              float* __restrict__ sums) {
    const int cq = threadIdx.x & 31;   // column quad: cols 4*cq .. 4*cq+3
    const int rg = threadIdx.x >> 5;   // row group 0..7 within block
    float4 a0 = {0.f, 0.f, 0.f, 0.f};
    float4 a1 = {0.f, 0.f, 0.f, 0.f};
    const int stride = gridDim.x * 8;
    for (int n = blockIdx.x * 8 + rg; n < NN; n += stride) {
        float4 v = nodes4[n * 32 + cq];
        float m0 = flags[n]      ? 1.f : 0.f;
        float m1 = flags[NN + n] ? 1.f : 0.f;
        a0.x = fmaf(v.x, m0, a0.x); a0.y = fmaf(v.y, m0, a0.y);
        a0.z = fmaf(v.z, m0, a0.z); a0.w = fmaf(v.w, m0, a0.w);
        a1.x = fmaf(v.x, m1, a1.x); a1.y = fmaf(v.y, m1, a1.y);
        a1.z = fmaf(v.z, m1, a1.z); a1.w = fmaf(v.w, m1, a1.w);
    }
    __shared__ float sh[256];          // [s][col] flattened
    sh[threadIdx.x] = 0.f;
    __syncthreads();
    atomicAdd(&sh[4 * cq + 0],       a0.x);
    atomicAdd(&sh[4 * cq + 1],       a0.y);
    atomicAdd(&sh[4 * cq + 2],       a0.z);
    atomicAdd(&sh[4 * cq + 3],       a0.w);
    atomicAdd(&sh[128 + 4 * cq + 0], a1.x);
    atomicAdd(&sh[128 + 4 * cq + 1], a1.y);
    atomicAdd(&sh[128 + 4 * cq + 2], a1.z);
    atomicAdd(&sh[128 + 4 * cq + 3], a1.w);
    __syncthreads();
    atomicAdd(&sums[threadIdx.x], sh[threadIdx.x]);
}

// g = (sums0 @ W0 + sums1 @ W1) / N, then 3-layer MLP, single block of 128.
__global__ __launch_bounds__(128) void k_final(const float* __restrict__ sums,
                                               const float* __restrict__ W,
                                               const float* __restrict__ pt,
                                               const float* __restrict__ fc1w,
                                               const float* __restrict__ fc1b,
                                               const float* __restrict__ fc2w,
                                               const float* __restrict__ fc2b,
                                               const float* __restrict__ fc3w,
                                               const float* __restrict__ fc3b,
                                               float* __restrict__ out) {
    __shared__ float s0[DD], s1[DD], x[DD + 4], y1[HIDN], y2[HIDN];
    const int t = threadIdx.x;
    s0[t] = sums[t];
    s1[t] = sums[DD + t];
    __syncthreads();
    float g = 0.f;
    #pragma unroll 4
    for (int k = 0; k < DD; ++k) {
        g = fmaf(s0[k], W[k * DD + t], g);            // W[0][k][t]
        g = fmaf(s1[k], W[DD * DD + k * DD + t], g);  // W[1][k][t]
    }
    x[t] = g * (1.0f / (float)NN);
    if (t == 0) x[DD] = pt[0];
    __syncthreads();
    if (t < HIDN) {
        float acc = fc1b[t];
        #pragma unroll 4
        for (int j = 0; j < DD + 1; ++j) acc = fmaf(x[j], fc1w[t * (DD + 1) + j], acc);
        y1[t] = leaky(acc);
    }
    __syncthreads();
    if (t < HIDN) {
        float acc = fc2b[t];
        #pragma unroll 4
        for (int j = 0; j < HIDN; ++j) acc = fmaf(y1[j], fc2w[t * HIDN + j], acc);
        y2[t] = leaky(acc);
    }
    __syncthreads();
    if (t < 2) {
        float acc = fc3b[t];
        for (int j = 0; j < HIDN; ++j) acc = fmaf(y2[j], fc3w[t * HIDN + j], acc);
        out[t] = acc;
    }
}

extern "C" void kernel_launch(void* const* d_in, const int* in_sizes, int n_in,
                              void* d_out, int out_size, void* d_ws, size_t ws_size,
                              hipStream_t stream) {
    const float4* nodes4 = (const float4*)d_in[0];   // fp32 (N,128)
    const int2*   edges  = (const int2*)d_in[1];     // int32 (S,E,2)
    const float*  pt     = (const float*)d_in[2];    // fp32 (1,1)
    const float*  W      = (const float*)d_in[3];    // fp32 (S,D,D)
    // d_in[4]=att_w, d_in[5]=att_b: provably unused (softmax weights sum to 1)
    const float*  fc1w   = (const float*)d_in[6];
    const float*  fc1b   = (const float*)d_in[7];
    const float*  fc2w   = (const float*)d_in[8];
    const float*  fc2b   = (const float*)d_in[9];
    const float*  fc3w   = (const float*)d_in[10];
    const float*  fc3b   = (const float*)d_in[11];
    float* out = (float*)d_out;

    float*   sums  = (float*)d_ws;                 // 256 floats
    uint8_t* flags = (uint8_t*)d_ws + 1024;        // 2*N bytes

    hipMemsetAsync(d_ws, 0, 1024 + (size_t)SS * NN, stream);
    k_flags<<<(SS * EE + 255) / 256, 256, 0, stream>>>(edges, flags);
    k_msum<<<512, 256, 0, stream>>>(nodes4, flags, sums);
    k_final<<<1, 128, 0, stream>>>(sums, W, pt, fc1w, fc1b, fc2w, fc2b,
                                   fc3w, fc3b, out);
}

// Round 3
// 136.290 us; speedup vs baseline: 1.1647x; 1.1647x over previous
//
#include <hip/hip_runtime.h>
#include <stdint.h>

// GAT_88252987998923 — analytic collapse (exact; absmax 0.0 in R2):
//   g = (1/N) * Σ_s (Σ_{n: indeg_s(n)>0} nodes[n]) @ W[s]
// then the 3-layer MLP. att_w/att_b/softmax cancel (softmax sums to 1 per dst
// segment; scatter target irrelevant under mean).
// R3 changes: k_final parallel-load rewrite (1024 thr, LDS-staged MLP weights,
// reg-staged W) — was 44 µs latency-bound on 1 block. k_msum 1024 blocks +
// 2-row ILP + 8-way replicated global accumulators.

#define NN   100000
#define DD   128
#define EE   600000
#define SS   2
#define HIDN 80
#define MS_BLOCKS 1024

__device__ __forceinline__ float leaky(float x) { return x > 0.f ? x : 0.01f * x; }

// Mark nodes that have >=1 incoming edge per edge-set s. Races benign (store 1).
// int4 load = 2 edges/thread (16 B/lane coalescing sweet spot).
__global__ __launch_bounds__(256) void k_flags(const int4* __restrict__ e4,
                                               uint8_t* __restrict__ flags) {
    int i = blockIdx.x * 256 + threadIdx.x;          // pair index, SS*EE/2 total
    if (i < SS * EE / 2) {
        int4 v = e4[i];                              // (src0,dst0,src1,dst1)
        int s = (i >= EE / 2) ? 1 : 0;
        flags[s * NN + v.y] = 1;
        flags[s * NN + v.w] = 1;
    }
}

// Masked column sums into 8 replicated accumulators (contention /8):
// sums8[r][s*128+d] partial of Σ_{n: flags[s][n]} nodes[n][d]
__global__ __launch_bounds__(256) void k_msum(const float4* __restrict__ nodes4,
                                              const uint8_t* __restrict__ flags,
                                              float* __restrict__ sums8) {
    const int cq = threadIdx.x & 31;   // column quad: cols 4*cq .. 4*cq+3
    const int rg = threadIdx.x >> 5;   // row group 0..7 within block
    float4 a0 = {0.f, 0.f, 0.f, 0.f};
    float4 a1 = {0.f, 0.f, 0.f, 0.f};
    const int stride = MS_BLOCKS * 8;  // 8192 rows per slot
    for (int n = blockIdx.x * 8 + rg; n < NN; n += 2 * stride) {
        // row 1
        float4 v = nodes4[n * 32 + cq];
        float m0 = flags[n]      ? 1.f : 0.f;
        float m1 = flags[NN + n] ? 1.f : 0.f;
        // row 2 (independent load in flight with row 1)
        int n2 = n + stride;
        float4 v2 = {0.f, 0.f, 0.f, 0.f};
        float p0 = 0.f, p1 = 0.f;
        if (n2 < NN) {
            v2 = nodes4[n2 * 32 + cq];
            p0 = flags[n2]      ? 1.f : 0.f;
            p1 = flags[NN + n2] ? 1.f : 0.f;
        }
        a0.x = fmaf(v.x, m0, a0.x); a0.y = fmaf(v.y, m0, a0.y);
        a0.z = fmaf(v.z, m0, a0.z); a0.w = fmaf(v.w, m0, a0.w);
        a1.x = fmaf(v.x, m1, a1.x); a1.y = fmaf(v.y, m1, a1.y);
        a1.z = fmaf(v.z, m1, a1.z); a1.w = fmaf(v.w, m1, a1.w);
        a0.x = fmaf(v2.x, p0, a0.x); a0.y = fmaf(v2.y, p0, a0.y);
        a0.z = fmaf(v2.z, p0, a0.z); a0.w = fmaf(v2.w, p0, a0.w);
        a1.x = fmaf(v2.x, p1, a1.x); a1.y = fmaf(v2.y, p1, a1.y);
        a1.z = fmaf(v2.z, p1, a1.z); a1.w = fmaf(v2.w, p1, a1.w);
    }
    __shared__ float sh[256];          // [s][col] flattened
    sh[threadIdx.x] = 0.f;
    __syncthreads();
    atomicAdd(&sh[4 * cq + 0],       a0.x);
    atomicAdd(&sh[4 * cq + 1],       a0.y);
    atomicAdd(&sh[4 * cq + 2],       a0.z);
    atomicAdd(&sh[4 * cq + 3],       a0.w);
    atomicAdd(&sh[128 + 4 * cq + 0], a1.x);
    atomicAdd(&sh[128 + 4 * cq + 1], a1.y);
    atomicAdd(&sh[128 + 4 * cq + 2], a1.z);
    atomicAdd(&sh[128 + 4 * cq + 3], a1.w);
    __syncthreads();
    atomicAdd(&sums8[(blockIdx.x & 7) * 256 + threadIdx.x], sh[threadIdx.x]);
}

// g = (sums0 @ W0 + sums1 @ W1) / N, then 3-layer MLP.
// 1024 threads: all global loads issued in parallel before one barrier —
// MLP weights staged to LDS, W staged to registers (32/thread).
__global__ __launch_bounds__(1024) void k_final(const float* __restrict__ sums8,
                                                const float* __restrict__ W,
                                                const float* __restrict__ pt,
                                                const float* __restrict__ fc1w,
                                                const float* __restrict__ fc1b,
                                                const float* __restrict__ fc2w,
                                                const float* __restrict__ fc2b,
                                                const float* __restrict__ fc3w,
                                                const float* __restrict__ fc3b,
                                                float* __restrict__ out) {
    __shared__ float s01[2 * DD];
    __shared__ float fc1w_s[HIDN * 129];     // stride 129 (odd -> 2-way LDS, free)
    __shared__ float fc2w_s[HIDN * 81];      // padded stride 81 (odd)
    __shared__ float fc3w_s[2 * HIDN];
    __shared__ float fc1b_s[HIDN], fc2b_s[HIDN], fc3b_s[2];
    __shared__ float part[8][DD];
    __shared__ float x[DD + 4], y1[HIDN], y2[HIDN];

    const int tid = threadIdx.x;
    const int c = tid >> 7;        // k-chunk 0..7
    const int t = tid & 127;       // output column

    // ---- phase A: issue ALL independent global loads ----
    if (tid < 256) {               // reduce 8 sums replicas
        float s = 0.f;
        #pragma unroll
        for (int r = 0; r < 8; ++r) s += sums8[r * 256 + tid];
        s01[tid] = s;
    }
    float w0[16], w1[16];
    #pragma unroll
    for (int k = 0; k < 16; ++k) {
        w0[k] = W[(c * 16 + k) * DD + t];             // W[0][k][t]
        w1[k] = W[DD * DD + (c * 16 + k) * DD + t];   // W[1][k][t]
    }
    for (int i = tid; i < HIDN * 129; i += 1024) fc1w_s[i] = fc1w[i];
    for (int i = tid; i < HIDN * HIDN; i += 1024)
        fc2w_s[(i / HIDN) * 81 + (i % HIDN)] = fc2w[i];
    if (tid < 2 * HIDN) fc3w_s[tid] = fc3w[tid];
    if (tid >= 512 && tid < 512 + HIDN) fc1b_s[tid - 512] = fc1b[tid - 512];
    if (tid >= 640 && tid < 640 + HIDN) fc2b_s[tid - 640] = fc2b[tid - 640];
    if (tid >= 768 && tid < 770) fc3b_s[tid - 768] = fc3b[tid - 768];
    float ptv = (tid == 1023) ? pt[0] : 0.f;
    __syncthreads();

    // ---- matvec partials ----
    float p = 0.f;
    #pragma unroll
    for (int k = 0; k < 16; ++k)
        p = fmaf(s01[c * 16 + k], w0[k], fmaf(s01[DD + c * 16 + k], w1[k], p));
    part[c][t] = p;
    __syncthreads();

    if (tid < DD) {
        float g = 0.f;
        #pragma unroll
        for (int cc = 0; cc < 8; ++cc) g += part[cc][tid];
        x[tid] = g * (1.0f / (float)NN);
    }
    if (tid == 1023) x[DD] = ptv;
    __syncthreads();

    if (tid < HIDN) {
        float acc = fc1b_s[tid];
        #pragma unroll 4
        for (int j = 0; j < DD + 1; ++j) acc = fmaf(x[j], fc1w_s[tid * 129 + j], acc);
        y1[tid] = leaky(acc);
    }
    __syncthreads();
    if (tid < HIDN) {
        float acc = fc2b_s[tid];
        #pragma unroll 4
        for (int j = 0; j < HIDN; ++j) acc = fmaf(y1[j], fc2w_s[tid * 81 + j], acc);
        y2[tid] = leaky(acc);
    }
    __syncthreads();
    if (tid < 2) {
        float acc = fc3b_s[tid];
        for (int j = 0; j < HIDN; ++j) acc = fmaf(y2[j], fc3w_s[tid * HIDN + j], acc);
        out[tid] = acc;
    }
}

extern "C" void kernel_launch(void* const* d_in, const int* in_sizes, int n_in,
                              void* d_out, int out_size, void* d_ws, size_t ws_size,
                              hipStream_t stream) {
    const float4* nodes4 = (const float4*)d_in[0];   // fp32 (N,128)
    const int4*   edges  = (const int4*)d_in[1];     // int32 (S,E,2), 2 edges/int4
    const float*  pt     = (const float*)d_in[2];    // fp32 (1,1)
    const float*  W      = (const float*)d_in[3];    // fp32 (S,D,D)
    // d_in[4]=att_w, d_in[5]=att_b: provably unused (softmax weights sum to 1)
    const float*  fc1w   = (const float*)d_in[6];
    const float*  fc1b   = (const float*)d_in[7];
    const float*  fc2w   = (const float*)d_in[8];
    const float*  fc2b   = (const float*)d_in[9];
    const float*  fc3w   = (const float*)d_in[10];
    const float*  fc3b   = (const float*)d_in[11];
    float* out = (float*)d_out;

    float*   sums8 = (float*)d_ws;                 // 8 * 256 floats = 8 KB
    uint8_t* flags = (uint8_t*)d_ws + 8192;        // 2*N bytes

    hipMemsetAsync(d_ws, 0, 8192 + (size_t)SS * NN, stream);
    k_flags<<<(SS * EE / 2 + 255) / 256, 256, 0, stream>>>(edges, flags);
    k_msum<<<MS_BLOCKS, 256, 0, stream>>>(nodes4, flags, sums8);
    k_final<<<1, 1024, 0, stream>>>(sums8, W, pt, fc1w, fc1b, fc2w, fc2b,
                                    fc3w, fc3b, out);
}